// Round 1
// baseline (453.910 us; speedup 1.0000x reference)
//
#include <hip/hip_runtime.h>
#include <math.h>

// EdgeDegreeEmbeddingNetwork — algebraically reduced form.
//   x0[u]   = exp_w[u] + exp_b[u]                                (128)
//   h1      = silu(LN(es @ W1 + b1))                             (E,64)
//   h2      = silu(LN(h1 @ W2 + b2))                             (E,64)
//   s       = h2 @ M + c        M: 64x224 folded from rad_w3/x0/proj_w*
//   feat[e] = [ y0*s0 + proj_b (128) | y1 ⊗ s1 (64*3) | y2 ⊗ s2 (32*5) ]
//   out[n]  = Σ_{dst(e)=n} feat[e] / sqrt(8)
// Only w[:,0:384] and proj_w*[0:128,:] are ever live (xs[1],xs[2]==0 and
// W3J(0,l,l)*sqrt(2l+1) == identity).

#define NEDGES 80000
#define NGROUPS (NEDGES / 4)

__device__ __forceinline__ float wave_sum64(float v) {
#pragma unroll
    for (int off = 32; off > 0; off >>= 1) v += __shfl_xor(v, off, 64);
    return v;
}

__device__ __forceinline__ float ln_silu(float x, float g, float b) {
    float mu  = wave_sum64(x) * (1.0f / 64.0f);
    float d   = x - mu;
    float var = wave_sum64(d * d) * (1.0f / 64.0f);
    float y   = d * rsqrtf(var + 1e-5f) * g + b;
    return y / (1.0f + __expf(-y));
}

// ---- Precompute M (64x224) and c (224) into workspace -----------------------
__global__ __launch_bounds__(256) void precompute_Mc(
    const float* __restrict__ exp_w, const float* __restrict__ exp_b,
    const float* __restrict__ rad_w3,     // 64 x 960
    const float* __restrict__ rad_offset, // 960
    const float* __restrict__ proj_w0,    // 224 x 128 (rows 0..127 live)
    const float* __restrict__ proj_w1,    // 384 x 64
    const float* __restrict__ proj_w2,    // 352 x 32
    float* __restrict__ M, float* __restrict__ cvec)
{
    __shared__ float x0[128];
    int t = threadIdx.x;
    if (t < 128) x0[t] = exp_w[t] + exp_b[t];
    __syncthreads();
    if (t >= 224) return;
    int h = blockIdx.x; // 0..63 -> M rows, 64 -> c
    const float* src = (h < 64) ? (rad_w3 + h * 960) : rad_offset;
    float acc = 0.0f;
    if (t < 128) {
#pragma unroll 4
        for (int u = 0; u < 128; ++u) acc += src[u] * x0[u] * proj_w0[u * 128 + t];
    } else if (t < 192) {
        int o = t - 128;
#pragma unroll 4
        for (int u = 0; u < 128; ++u) acc += src[128 + u] * x0[u] * proj_w1[u * 64 + o];
    } else {
        int o = t - 192;
#pragma unroll 4
        for (int u = 0; u < 128; ++u) acc += src[256 + u] * x0[u] * proj_w2[u * 32 + o];
    }
    if (h < 64) M[h * 224 + t] = acc;
    else        cvec[t] = acc;
}

// ---- Fused main kernel: one wave handles 4 edges ----------------------------
__global__ __launch_bounds__(256) void edge_fused(
    const float* __restrict__ edge_attr,    // E x 9
    const float* __restrict__ edge_scalars, // E x 128
    const int*   __restrict__ edge_dst,     // E
    const float* __restrict__ rad_w1,       // 128 x 64
    const float* __restrict__ rad_b1,
    const float* __restrict__ g1, const float* __restrict__ bt1,
    const float* __restrict__ rad_w2,       // 64 x 64
    const float* __restrict__ rad_b2,
    const float* __restrict__ g2, const float* __restrict__ bt2,
    const float* __restrict__ proj_b,       // 128
    const float* __restrict__ M,            // 64 x 224
    const float* __restrict__ cvec,         // 224
    float* __restrict__ out)                // 10000 x 480 (pre-zeroed)
{
    const int lane = threadIdx.x & 63;
    const int gid  = (blockIdx.x << 2) | (threadIdx.x >> 6);
    if (gid >= NGROUPS) return;
    const int e0 = gid * 4;
    constexpr float inv_s8 = 0.35355339059327373f; // 1/sqrt(8)

    // ---------------- GEMM1: a_e[lane] = b1[lane] + sum_u es[e][u]*W1[u][lane]
    float a0, a1, a2, a3;
    {
        float b = rad_b1[lane];
        a0 = a1 = a2 = a3 = b;
    }
    const float* es = edge_scalars + (size_t)e0 * 128;
#pragma unroll 4
    for (int u = 0; u < 128; u += 4) {
        float4 v0 = *(const float4*)(es + u);
        float4 v1 = *(const float4*)(es + 128 + u);
        float4 v2 = *(const float4*)(es + 256 + u);
        float4 v3 = *(const float4*)(es + 384 + u);
        float w0 = rad_w1[(u + 0) * 64 + lane];
        float w1 = rad_w1[(u + 1) * 64 + lane];
        float w2 = rad_w1[(u + 2) * 64 + lane];
        float w3 = rad_w1[(u + 3) * 64 + lane];
        a0 += w0 * v0.x + w1 * v0.y + w2 * v0.z + w3 * v0.w;
        a1 += w0 * v1.x + w1 * v1.y + w2 * v1.z + w3 * v1.w;
        a2 += w0 * v2.x + w1 * v2.y + w2 * v2.z + w3 * v2.w;
        a3 += w0 * v3.x + w1 * v3.y + w2 * v3.z + w3 * v3.w;
    }

    // ---------------- LN1 + silu
    float h1_0, h1_1, h1_2, h1_3;
    {
        float g = g1[lane], b = bt1[lane];
        h1_0 = ln_silu(a0, g, b);
        h1_1 = ln_silu(a1, g, b);
        h1_2 = ln_silu(a2, g, b);
        h1_3 = ln_silu(a3, g, b);
    }

    // ---------------- GEMM2 via shuffle broadcast
    float c0, c1, c2, c3;
    {
        float b = rad_b2[lane];
        c0 = c1 = c2 = c3 = b;
    }
    for (int u = 0; u < 64; ++u) {
        float w = rad_w2[u * 64 + lane];
        c0 += w * __shfl(h1_0, u, 64);
        c1 += w * __shfl(h1_1, u, 64);
        c2 += w * __shfl(h1_2, u, 64);
        c3 += w * __shfl(h1_3, u, 64);
    }

    // ---------------- LN2 + silu
    float h2v[4];
    {
        float g = g2[lane], b = bt2[lane];
        h2v[0] = ln_silu(c0, g, b);
        h2v[1] = ln_silu(c1, g, b);
        h2v[2] = ln_silu(c2, g, b);
        h2v[3] = ln_silu(c3, g, b);
    }

    // ---------------- s = h2 @ M + c   (lane holds cols lane, 64+lane, 128+lane, 192+(lane&31))
    const int l32 = lane & 31;
    float sA[4], sB[4], sC[4], sD[4];
    {
        float cA = cvec[lane], cB = cvec[64 + lane], cC = cvec[128 + lane], cD = cvec[192 + l32];
#pragma unroll
        for (int e = 0; e < 4; ++e) { sA[e] = cA; sB[e] = cB; sC[e] = cC; sD[e] = cD; }
    }
    for (int u = 0; u < 64; ++u) {
        const float* Mu = M + u * 224;
        float m0 = Mu[lane];
        float m1 = Mu[64 + lane];
        float m2 = Mu[128 + lane];
        float m3 = Mu[192 + l32];
#pragma unroll
        for (int e = 0; e < 4; ++e) {
            float h = __shfl(h2v[e], u, 64);
            sA[e] += m0 * h; sB[e] += m1 * h; sC[e] += m2 * h; sD[e] += m3 * h;
        }
    }

    // ---------------- features + atomic scatter
    float pb0 = proj_b[lane], pb1 = proj_b[64 + lane];
#pragma unroll
    for (int e = 0; e < 4; ++e) {
        int eid = e0 + e;
        const float* ya = edge_attr + (size_t)eid * 9;
        float y0 = ya[0];
        int dst = edge_dst[eid];
        float* ob = out + (size_t)dst * 480;
        atomicAdd(ob + lane,      (y0 * sA[e] + pb0) * inv_s8);
        atomicAdd(ob + 64 + lane, (y0 * sB[e] + pb1) * inv_s8);
        float cv = sC[e] * inv_s8;
        atomicAdd(ob + 128 + lane * 3 + 0, ya[1] * cv);
        atomicAdd(ob + 128 + lane * 3 + 1, ya[2] * cv);
        atomicAdd(ob + 128 + lane * 3 + 2, ya[3] * cv);
        if (lane < 32) {
            float dv = sD[e] * inv_s8;
            atomicAdd(ob + 320 + lane * 5 + 0, ya[4] * dv);
            atomicAdd(ob + 320 + lane * 5 + 1, ya[5] * dv);
            atomicAdd(ob + 320 + lane * 5 + 2, ya[6] * dv);
            atomicAdd(ob + 320 + lane * 5 + 3, ya[7] * dv);
            atomicAdd(ob + 320 + lane * 5 + 4, ya[8] * dv);
        }
    }
}

extern "C" void kernel_launch(void* const* d_in, const int* in_sizes, int n_in,
                              void* d_out, int out_size, void* d_ws, size_t ws_size,
                              hipStream_t stream)
{
    const float* edge_attr    = (const float*)d_in[1];
    const float* edge_scalars = (const float*)d_in[2];
    const int*   edge_dst     = (const int*)d_in[4];
    const float* exp_w   = (const float*)d_in[6];
    const float* exp_b   = (const float*)d_in[7];
    const float* rad_w1  = (const float*)d_in[8];
    const float* rad_b1  = (const float*)d_in[9];
    const float* g1      = (const float*)d_in[10];
    const float* bt1     = (const float*)d_in[11];
    const float* rad_w2  = (const float*)d_in[12];
    const float* rad_b2  = (const float*)d_in[13];
    const float* g2      = (const float*)d_in[14];
    const float* bt2     = (const float*)d_in[15];
    const float* rad_w3  = (const float*)d_in[16];
    const float* rad_off = (const float*)d_in[17];
    const float* pw0     = (const float*)d_in[18];
    const float* pw1     = (const float*)d_in[19];
    const float* pw2     = (const float*)d_in[20];
    const float* proj_b  = (const float*)d_in[21];

    float* M    = (float*)d_ws;   // 64*224 floats
    float* cvec = M + 64 * 224;   // 224 floats

    hipMemsetAsync(d_out, 0, (size_t)out_size * sizeof(float), stream);
    precompute_Mc<<<65, 256, 0, stream>>>(exp_w, exp_b, rad_w3, rad_off, pw0, pw1, pw2, M, cvec);
    edge_fused<<<NGROUPS / 4, 256, 0, stream>>>(edge_attr, edge_scalars, edge_dst,
        rad_w1, rad_b1, g1, bt1, rad_w2, rad_b2, g2, bt2, proj_b, M, cvec, (float*)d_out);
}

// Round 2
// 254.843 us; speedup vs baseline: 1.7811x; 1.7811x over previous
//
#include <hip/hip_runtime.h>
#include <math.h>

// EdgeDegreeEmbeddingNetwork — algebraically reduced, scatter-free.
//
//   x0[u]   = exp_w[u] + exp_b[u]
//   h2      = silu(LN(silu(LN(es@W1+b1))@W2+b2))            (E,64)
//   s       = h2 @ M + c        (M 64x224 folded from rad_w3/x0/proj_w*)
//   feat[e] = [ y0*s0 + proj_b | y1 ⊗ s1 | y2 ⊗ s2 ]        (480)
//   out[n]  = Σ_{dst(e)=n} feat[e] / sqrt(8)
//
// Linearity: out[n] = contract(M, T[n]) + c ⊗ ysum[n] + cnt[n]*proj_b
// where T[n][u][k] = Σ_{e→n} h2[e,u]*y[e,k]  (64x9 per node, in registers).
// Pipeline: edge_h2 (+histogram) -> scan -> scatter (CSR) -> node_gather.
// No atomics on the 480-wide output => WRITE_SIZE 470MB -> ~42MB.

#define NEDGES 80000
#define NNODES 10000

__device__ __forceinline__ float wave_sum64(float v) {
#pragma unroll
    for (int off = 32; off > 0; off >>= 1) v += __shfl_xor(v, off, 64);
    return v;
}

__device__ __forceinline__ float ln_silu(float x, float g, float b) {
    float mu  = wave_sum64(x) * (1.0f / 64.0f);
    float d   = x - mu;
    float var = wave_sum64(d * d) * (1.0f / 64.0f);
    float y   = d * rsqrtf(var + 1e-5f) * g + b;
    return y / (1.0f + __expf(-y));
}

// ---- Precompute M (64x224) and c (224) --------------------------------------
__global__ __launch_bounds__(256) void precompute_Mc(
    const float* __restrict__ exp_w, const float* __restrict__ exp_b,
    const float* __restrict__ rad_w3,     // 64 x 960
    const float* __restrict__ rad_offset, // 960
    const float* __restrict__ proj_w0,    // 224 x 128 (rows 0..127 live)
    const float* __restrict__ proj_w1,    // 384 x 64
    const float* __restrict__ proj_w2,    // 352 x 32
    float* __restrict__ M, float* __restrict__ cvec)
{
    __shared__ float x0[128];
    int t = threadIdx.x;
    if (t < 128) x0[t] = exp_w[t] + exp_b[t];
    __syncthreads();
    if (t >= 224) return;
    int h = blockIdx.x; // 0..63 -> M rows, 64 -> c
    const float* src = (h < 64) ? (rad_w3 + h * 960) : rad_offset;
    float acc = 0.0f;
    if (t < 128) {
#pragma unroll 4
        for (int u = 0; u < 128; ++u) acc += src[u] * x0[u] * proj_w0[u * 128 + t];
    } else if (t < 192) {
        int o = t - 128;
#pragma unroll 4
        for (int u = 0; u < 128; ++u) acc += src[128 + u] * x0[u] * proj_w1[u * 64 + o];
    } else {
        int o = t - 192;
#pragma unroll 4
        for (int u = 0; u < 128; ++u) acc += src[256 + u] * x0[u] * proj_w2[u * 32 + o];
    }
    if (h < 64) M[h * 224 + t] = acc;
    else        cvec[t] = acc;
}

// ---- Phase A: per-edge radial MLP -> h2, fused dst histogram ----------------
__global__ __launch_bounds__(256) void edge_h2(
    const float* __restrict__ edge_scalars, // E x 128
    const int*   __restrict__ edge_dst,     // E
    const float* __restrict__ rad_w1,       // 128 x 64
    const float* __restrict__ rad_b1,
    const float* __restrict__ g1, const float* __restrict__ bt1,
    const float* __restrict__ rad_w2,       // 64 x 64
    const float* __restrict__ rad_b2,
    const float* __restrict__ g2, const float* __restrict__ bt2,
    float* __restrict__ h2buf,              // E x 64
    int*   __restrict__ counts)             // NNODES (pre-zeroed)
{
    const int lane = threadIdx.x & 63;
    const int gid  = (blockIdx.x << 2) | (threadIdx.x >> 6);
    const int e0   = gid * 4;

    float a0, a1, a2, a3;
    {
        float b = rad_b1[lane];
        a0 = a1 = a2 = a3 = b;
    }
    const float* es = edge_scalars + (size_t)e0 * 128;
#pragma unroll 4
    for (int u = 0; u < 128; u += 4) {
        float4 v0 = *(const float4*)(es + u);
        float4 v1 = *(const float4*)(es + 128 + u);
        float4 v2 = *(const float4*)(es + 256 + u);
        float4 v3 = *(const float4*)(es + 384 + u);
        float w0 = rad_w1[(u + 0) * 64 + lane];
        float w1 = rad_w1[(u + 1) * 64 + lane];
        float w2 = rad_w1[(u + 2) * 64 + lane];
        float w3 = rad_w1[(u + 3) * 64 + lane];
        a0 += w0 * v0.x + w1 * v0.y + w2 * v0.z + w3 * v0.w;
        a1 += w0 * v1.x + w1 * v1.y + w2 * v1.z + w3 * v1.w;
        a2 += w0 * v2.x + w1 * v2.y + w2 * v2.z + w3 * v2.w;
        a3 += w0 * v3.x + w1 * v3.y + w2 * v3.z + w3 * v3.w;
    }

    float h1_0, h1_1, h1_2, h1_3;
    {
        float g = g1[lane], b = bt1[lane];
        h1_0 = ln_silu(a0, g, b);
        h1_1 = ln_silu(a1, g, b);
        h1_2 = ln_silu(a2, g, b);
        h1_3 = ln_silu(a3, g, b);
    }

    float c0, c1, c2, c3;
    {
        float b = rad_b2[lane];
        c0 = c1 = c2 = c3 = b;
    }
    for (int u = 0; u < 64; ++u) {
        float w = rad_w2[u * 64 + lane];
        c0 += w * __shfl(h1_0, u, 64);
        c1 += w * __shfl(h1_1, u, 64);
        c2 += w * __shfl(h1_2, u, 64);
        c3 += w * __shfl(h1_3, u, 64);
    }

    {
        float g = g2[lane], b = bt2[lane];
        h2buf[(size_t)(e0 + 0) * 64 + lane] = ln_silu(c0, g, b);
        h2buf[(size_t)(e0 + 1) * 64 + lane] = ln_silu(c1, g, b);
        h2buf[(size_t)(e0 + 2) * 64 + lane] = ln_silu(c2, g, b);
        h2buf[(size_t)(e0 + 3) * 64 + lane] = ln_silu(c3, g, b);
    }
    if (lane < 4) atomicAdd(&counts[edge_dst[e0 + lane]], 1);
}

// ---- CSR: exclusive scan of counts (single block), zero cursors -------------
__global__ __launch_bounds__(1024) void scan_counts(
    int* __restrict__ counts,   // in: counts, out: zeroed (reused as cursor)
    int* __restrict__ offsets)  // NNODES+1
{
    __shared__ int part[1024];
    const int t = threadIdx.x;
    const int base = t * 10;
    int local[10];
    int s = 0;
#pragma unroll
    for (int i = 0; i < 10; ++i) {
        int idx = base + i;
        int v = (idx < NNODES) ? counts[idx] : 0;
        local[i] = s;
        s += v;
    }
    part[t] = s;
    __syncthreads();
    for (int off = 1; off < 1024; off <<= 1) {
        int v = (t >= off) ? part[t - off] : 0;
        __syncthreads();
        part[t] += v;
        __syncthreads();
    }
    int pre = (t == 0) ? 0 : part[t - 1];
#pragma unroll
    for (int i = 0; i < 10; ++i) {
        int idx = base + i;
        if (idx < NNODES) {
            offsets[idx] = pre + local[i];
            counts[idx] = 0; // becomes the scatter cursor
        }
    }
    if (t == 1023) offsets[NNODES] = part[1023];
}

// ---- CSR: scatter edge ids sorted by dst ------------------------------------
__global__ __launch_bounds__(256) void scatter_edges(
    const int* __restrict__ edge_dst,
    const int* __restrict__ offsets,
    int* __restrict__ cursor,
    int* __restrict__ order)
{
    int e = blockIdx.x * 256 + threadIdx.x;
    if (e >= NEDGES) return;
    int d = edge_dst[e];
    int pos = offsets[d] + atomicAdd(&cursor[d], 1);
    order[pos] = e;
}

// ---- Phase B: one wave per node, T-accumulate + M-contract, plain writes ----
__global__ __launch_bounds__(256) void node_gather(
    const float* __restrict__ h2buf,     // E x 64
    const float* __restrict__ edge_attr, // E x 9
    const int*   __restrict__ offsets,   // NNODES+1
    const int*   __restrict__ order,     // E
    const float* __restrict__ M,         // 64 x 224
    const float* __restrict__ cvec,      // 224
    const float* __restrict__ proj_b,    // 128
    float* __restrict__ out)             // NNODES x 480
{
    __shared__ float ldsM[64 * 224];
    __shared__ float ldsC[224];
    for (int i = threadIdx.x; i < 64 * 224; i += 256) ldsM[i] = M[i];
    for (int i = threadIdx.x; i < 224; i += 256) ldsC[i] = cvec[i];
    __syncthreads();

    const int lane = threadIdx.x & 63;
    const int n = blockIdx.x * 4 + (threadIdx.x >> 6);
    if (n >= NNODES) return;
    const int s0 = offsets[n], s1 = offsets[n + 1];

    float T[9] = {0, 0, 0, 0, 0, 0, 0, 0, 0};
    float ysum[9] = {0, 0, 0, 0, 0, 0, 0, 0, 0};
    for (int i = s0; i < s1; ++i) {
        int e = order[i];
        float hv = h2buf[(size_t)e * 64 + lane];
        const float* ya = edge_attr + (size_t)e * 9;
#pragma unroll
        for (int k = 0; k < 9; ++k) {
            float y = ya[k];
            T[k] += hv * y;
            ysum[k] += y;
        }
    }

    const int l32 = lane & 31;
    float acc0a = 0.0f, acc0b = 0.0f;
    float acc1[3] = {0, 0, 0};
    float acc2[5] = {0, 0, 0, 0, 0};
    for (int u = 0; u < 64; ++u) {
        const float* Mu = ldsM + u * 224;
        float m0a = Mu[lane];
        float m0b = Mu[64 + lane];
        float m1  = Mu[128 + lane];
        float m2  = Mu[192 + l32];
        float t0 = __shfl(T[0], u, 64);
        acc0a += m0a * t0;
        acc0b += m0b * t0;
#pragma unroll
        for (int k = 0; k < 3; ++k) acc1[k] += m1 * __shfl(T[1 + k], u, 64);
#pragma unroll
        for (int k = 0; k < 5; ++k) acc2[k] += m2 * __shfl(T[4 + k], u, 64);
    }

    constexpr float inv_s8 = 0.35355339059327373f; // 1/sqrt(8)
    const float cnt = (float)(s1 - s0);
    float* ob = out + (size_t)n * 480;
    ob[lane]      = (acc0a + ldsC[lane] * ysum[0]      + cnt * proj_b[lane])      * inv_s8;
    ob[64 + lane] = (acc0b + ldsC[64 + lane] * ysum[0] + cnt * proj_b[64 + lane]) * inv_s8;
#pragma unroll
    for (int k = 0; k < 3; ++k)
        ob[128 + lane * 3 + k] = (acc1[k] + ldsC[128 + lane] * ysum[1 + k]) * inv_s8;
    if (lane < 32) {
#pragma unroll
        for (int k = 0; k < 5; ++k)
            ob[320 + lane * 5 + k] = (acc2[k] + ldsC[192 + lane] * ysum[4 + k]) * inv_s8;
    }
}

extern "C" void kernel_launch(void* const* d_in, const int* in_sizes, int n_in,
                              void* d_out, int out_size, void* d_ws, size_t ws_size,
                              hipStream_t stream)
{
    const float* edge_attr    = (const float*)d_in[1];
    const float* edge_scalars = (const float*)d_in[2];
    const int*   edge_dst     = (const int*)d_in[4];
    const float* exp_w   = (const float*)d_in[6];
    const float* exp_b   = (const float*)d_in[7];
    const float* rad_w1  = (const float*)d_in[8];
    const float* rad_b1  = (const float*)d_in[9];
    const float* g1      = (const float*)d_in[10];
    const float* bt1     = (const float*)d_in[11];
    const float* rad_w2  = (const float*)d_in[12];
    const float* rad_b2  = (const float*)d_in[13];
    const float* g2      = (const float*)d_in[14];
    const float* bt2     = (const float*)d_in[15];
    const float* rad_w3  = (const float*)d_in[16];
    const float* rad_off = (const float*)d_in[17];
    const float* pw0     = (const float*)d_in[18];
    const float* pw1     = (const float*)d_in[19];
    const float* pw2     = (const float*)d_in[20];
    const float* proj_b  = (const float*)d_in[21];

    // Workspace layout (~21 MB):
    float* M      = (float*)d_ws;               // 64*224 = 14336
    float* cvec   = M + 64 * 224;               // 224
    float* h2buf  = cvec + 224;                 // NEDGES*64 = 5,120,000
    int*   counts = (int*)(h2buf + (size_t)NEDGES * 64); // NNODES
    int*   offsets = counts + NNODES;           // NNODES+1
    int*   order   = offsets + NNODES + 1;      // NEDGES

    hipMemsetAsync(counts, 0, NNODES * sizeof(int), stream);
    precompute_Mc<<<65, 256, 0, stream>>>(exp_w, exp_b, rad_w3, rad_off, pw0, pw1, pw2, M, cvec);
    edge_h2<<<NEDGES / 16, 256, 0, stream>>>(edge_scalars, edge_dst,
        rad_w1, rad_b1, g1, bt1, rad_w2, rad_b2, g2, bt2, h2buf, counts);
    scan_counts<<<1, 1024, 0, stream>>>(counts, offsets);
    scatter_edges<<<(NEDGES + 255) / 256, 256, 0, stream>>>(edge_dst, offsets, counts, order);
    node_gather<<<(NNODES + 3) / 4, 256, 0, stream>>>(h2buf, edge_attr, offsets, order,
        M, cvec, proj_b, (float*)d_out);
}

// Round 3
// 155.389 us; speedup vs baseline: 2.9211x; 1.6400x over previous
//
#include <hip/hip_runtime.h>
#include <math.h>

// EdgeDegreeEmbeddingNetwork — algebraically reduced, scatter-free, CSR-ordered.
//
//   x0[u]   = exp_w[u] + exp_b[u]
//   h2      = silu(LN(silu(LN(es@W1+b1))@W2+b2))            (E,64)
//   out[n]  = contract(M, T[n]) + c ⊗ ysum[n] + cnt[n]*proj_b   (/sqrt 8)
//   T[n][u][k] = Σ_{e→n} h2[e,u]*y[e,k]
//
// Pipeline: memset -> [Mc + dst-histogram] -> scan -> scatter(pos, ya_csr)
//           -> edge_h2 (writes h2 rows in CSR order) -> node_gather (streaming).
// edge_h2: 8 edges/wave; es via readfirstlane-forced s_loads; GEMM2 via
// v_readlane (VALU, off the DS pipe); one-pass LN (sum+sumsq together).

#define NEDGES 80000
#define NNODES 10000

__device__ __forceinline__ float readlane_f(float v, int l) {
    return __builtin_bit_cast(float, __builtin_amdgcn_readlane(__builtin_bit_cast(int, v), l));
}

// ---- Fused: precompute M (64x224), c (224)  +  dst histogram ----------------
__global__ __launch_bounds__(256) void precompute_and_hist(
    const float* __restrict__ exp_w, const float* __restrict__ exp_b,
    const float* __restrict__ rad_w3,     // 64 x 960
    const float* __restrict__ rad_offset, // 960
    const float* __restrict__ proj_w0,    // 224 x 128 (rows 0..127 live)
    const float* __restrict__ proj_w1,    // 384 x 64
    const float* __restrict__ proj_w2,    // 352 x 32
    float* __restrict__ M, float* __restrict__ cvec,
    const int* __restrict__ edge_dst, int* __restrict__ counts)
{
    if (blockIdx.x >= 65) {
        // histogram blocks
        int b = blockIdx.x - 65;
        for (int e = b * 256 + threadIdx.x; e < NEDGES; e += 100 * 256)
            atomicAdd(&counts[edge_dst[e]], 1);
        return;
    }
    __shared__ float x0[128];
    int t = threadIdx.x;
    if (t < 128) x0[t] = exp_w[t] + exp_b[t];
    __syncthreads();
    if (t >= 224) return;
    int h = blockIdx.x; // 0..63 -> M rows, 64 -> c
    const float* src = (h < 64) ? (rad_w3 + h * 960) : rad_offset;
    float acc = 0.0f;
    if (t < 128) {
#pragma unroll 4
        for (int u = 0; u < 128; ++u) acc += src[u] * x0[u] * proj_w0[u * 128 + t];
    } else if (t < 192) {
        int o = t - 128;
#pragma unroll 4
        for (int u = 0; u < 128; ++u) acc += src[128 + u] * x0[u] * proj_w1[u * 64 + o];
    } else {
        int o = t - 192;
#pragma unroll 4
        for (int u = 0; u < 128; ++u) acc += src[256 + u] * x0[u] * proj_w2[u * 32 + o];
    }
    if (h < 64) M[h * 224 + t] = acc;
    else        cvec[t] = acc;
}

// ---- CSR: exclusive scan of counts (single block), zero cursors -------------
__global__ __launch_bounds__(1024) void scan_counts(
    int* __restrict__ counts,   // in: counts, out: zeroed (reused as cursor)
    int* __restrict__ offsets)  // NNODES+1
{
    __shared__ int part[1024];
    const int t = threadIdx.x;
    const int base = t * 10;
    int local[10];
    int s = 0;
#pragma unroll
    for (int i = 0; i < 10; ++i) {
        int idx = base + i;
        int v = (idx < NNODES) ? counts[idx] : 0;
        local[i] = s;
        s += v;
    }
    part[t] = s;
    __syncthreads();
    for (int off = 1; off < 1024; off <<= 1) {
        int v = (t >= off) ? part[t - off] : 0;
        __syncthreads();
        part[t] += v;
        __syncthreads();
    }
    int pre = (t == 0) ? 0 : part[t - 1];
#pragma unroll
    for (int i = 0; i < 10; ++i) {
        int idx = base + i;
        if (idx < NNODES) {
            offsets[idx] = pre + local[i];
            counts[idx] = 0; // becomes the scatter cursor
        }
    }
    if (t == 1023) offsets[NNODES] = part[1023];
}

// ---- CSR: per-edge position + gather edge_attr into CSR order ---------------
__global__ __launch_bounds__(256) void scatter_edges(
    const int*   __restrict__ edge_dst,
    const float* __restrict__ edge_attr, // E x 9
    const int*   __restrict__ offsets,
    int*   __restrict__ cursor,
    int*   __restrict__ pos_of,          // E
    float* __restrict__ ya_csr)          // E x 9
{
    int e = blockIdx.x * 256 + threadIdx.x;
    if (e >= NEDGES) return;
    int d = edge_dst[e];
    int pos = offsets[d] + atomicAdd(&cursor[d], 1);
    pos_of[e] = pos;
    const float* ya = edge_attr + (size_t)e * 9;
    float* dst = ya_csr + (size_t)pos * 9;
#pragma unroll
    for (int k = 0; k < 9; ++k) dst[k] = ya[k];
}

// ---- Phase A: per-edge radial MLP -> h2 rows written in CSR order -----------
__global__ __launch_bounds__(256) void edge_h2(
    const float* __restrict__ edge_scalars, // E x 128
    const int*   __restrict__ pos_of,       // E
    const float* __restrict__ rad_w1,       // 128 x 64
    const float* __restrict__ rad_b1,
    const float* __restrict__ g1, const float* __restrict__ bt1,
    const float* __restrict__ rad_w2,       // 64 x 64
    const float* __restrict__ rad_b2,
    const float* __restrict__ g2, const float* __restrict__ bt2,
    float* __restrict__ h2csr)              // E x 64 (CSR row order)
{
    const int lane = threadIdx.x & 63;
    const int wid  = threadIdx.x >> 6;
    const int e0   = __builtin_amdgcn_readfirstlane((blockIdx.x * 4 + wid) * 8);
    const float* es = edge_scalars + (size_t)e0 * 128;

    // ---------------- GEMM1: a[e] = b1[lane] + sum_u es[e][u]*W1[u][lane]
    float a[8];
    {
        float b = rad_b1[lane];
#pragma unroll
        for (int e = 0; e < 8; ++e) a[e] = b;
    }
#pragma unroll 2
    for (int u0 = 0; u0 < 128; u0 += 8) {
        float w[8];
#pragma unroll
        for (int j = 0; j < 8; ++j) w[j] = rad_w1[(u0 + j) * 64 + lane];
#pragma unroll
        for (int e = 0; e < 8; ++e) {
            float4 p = *(const float4*)(es + e * 128 + u0);
            float4 q = *(const float4*)(es + e * 128 + u0 + 4);
            a[e] += w[0] * p.x + w[1] * p.y + w[2] * p.z + w[3] * p.w
                  + w[4] * q.x + w[5] * q.y + w[6] * q.z + w[7] * q.w;
        }
    }

    // ---------------- LN1 + silu (one pass: sum & sumsq interleaved)
    float h1[8];
    {
        float s1v[8], s2v[8];
#pragma unroll
        for (int e = 0; e < 8; ++e) { s1v[e] = a[e]; s2v[e] = a[e] * a[e]; }
#pragma unroll
        for (int off = 32; off > 0; off >>= 1) {
#pragma unroll
            for (int e = 0; e < 8; ++e) {
                s1v[e] += __shfl_xor(s1v[e], off, 64);
                s2v[e] += __shfl_xor(s2v[e], off, 64);
            }
        }
        float g = g1[lane], b = bt1[lane];
#pragma unroll
        for (int e = 0; e < 8; ++e) {
            float mu  = s1v[e] * (1.0f / 64.0f);
            float var = s2v[e] * (1.0f / 64.0f) - mu * mu;
            float y   = (a[e] - mu) * rsqrtf(var + 1e-5f) * g + b;
            h1[e] = y / (1.0f + __expf(-y));
        }
    }

    // ---------------- GEMM2 via v_readlane (VALU, no DS pipe)
    float c[8];
    {
        float b = rad_b2[lane];
#pragma unroll
        for (int e = 0; e < 8; ++e) c[e] = b;
    }
#pragma unroll 8
    for (int u = 0; u < 64; ++u) {
        float w = rad_w2[u * 64 + lane];
#pragma unroll
        for (int e = 0; e < 8; ++e) c[e] += w * readlane_f(h1[e], u);
    }

    // ---------------- LN2 + silu, store rows at CSR positions
    {
        float s1v[8], s2v[8];
#pragma unroll
        for (int e = 0; e < 8; ++e) { s1v[e] = c[e]; s2v[e] = c[e] * c[e]; }
#pragma unroll
        for (int off = 32; off > 0; off >>= 1) {
#pragma unroll
            for (int e = 0; e < 8; ++e) {
                s1v[e] += __shfl_xor(s1v[e], off, 64);
                s2v[e] += __shfl_xor(s2v[e], off, 64);
            }
        }
        float g = g2[lane], b = bt2[lane];
#pragma unroll
        for (int e = 0; e < 8; ++e) {
            float mu  = s1v[e] * (1.0f / 64.0f);
            float var = s2v[e] * (1.0f / 64.0f) - mu * mu;
            float y   = (c[e] - mu) * rsqrtf(var + 1e-5f) * g + b;
            float h2v = y / (1.0f + __expf(-y));
            int p = pos_of[e0 + e]; // uniform -> s_load
            h2csr[(size_t)p * 64 + lane] = h2v;
        }
    }
}

// ---- Phase B: one wave per node, fully streaming reads, plain writes --------
__global__ __launch_bounds__(256) void node_gather(
    const float* __restrict__ h2csr,     // E x 64 (CSR order)
    const float* __restrict__ ya_csr,    // E x 9  (CSR order)
    const int*   __restrict__ offsets,   // NNODES+1
    const float* __restrict__ M,         // 64 x 224
    const float* __restrict__ cvec,      // 224
    const float* __restrict__ proj_b,    // 128
    float* __restrict__ out)             // NNODES x 480
{
    const int lane = threadIdx.x & 63;
    const int wid  = threadIdx.x >> 6;
    const int n = __builtin_amdgcn_readfirstlane(blockIdx.x * 4 + wid);
    const int s0 = offsets[n], s1 = offsets[n + 1];

    float T[9]  = {0, 0, 0, 0, 0, 0, 0, 0, 0};
    float ys[9] = {0, 0, 0, 0, 0, 0, 0, 0, 0};
    for (int i = s0; i < s1; ++i) {
        float hv = h2csr[(size_t)i * 64 + lane];      // coalesced stream
        const float* ya = ya_csr + (size_t)i * 9;     // uniform -> s_load
#pragma unroll
        for (int k = 0; k < 9; ++k) {
            float y = ya[k];
            T[k] += hv * y;
            ys[k] += y;
        }
    }

    const int l32 = lane & 31;
    float acc0a = 0.0f, acc0b = 0.0f;
    float acc1[3] = {0, 0, 0};
    float acc2[5] = {0, 0, 0, 0, 0};
#pragma unroll 4
    for (int u = 0; u < 64; ++u) {
        const float* Mu = M + u * 224;               // L1/L2-resident (57 KB)
        float m0a = Mu[lane];
        float m0b = Mu[64 + lane];
        float m1  = Mu[128 + lane];
        float m2  = Mu[192 + l32];
        float t0 = readlane_f(T[0], u);
        acc0a += m0a * t0;
        acc0b += m0b * t0;
#pragma unroll
        for (int k = 0; k < 3; ++k) acc1[k] += m1 * readlane_f(T[1 + k], u);
#pragma unroll
        for (int k = 0; k < 5; ++k) acc2[k] += m2 * readlane_f(T[4 + k], u);
    }

    constexpr float inv_s8 = 0.35355339059327373f; // 1/sqrt(8)
    const float cnt = (float)(s1 - s0);
    float* ob = out + (size_t)n * 480;
    ob[lane]      = (acc0a + cvec[lane] * ys[0]      + cnt * proj_b[lane])      * inv_s8;
    ob[64 + lane] = (acc0b + cvec[64 + lane] * ys[0] + cnt * proj_b[64 + lane]) * inv_s8;
#pragma unroll
    for (int k = 0; k < 3; ++k)
        ob[128 + lane * 3 + k] = (acc1[k] + cvec[128 + lane] * ys[1 + k]) * inv_s8;
    if (lane < 32) {
#pragma unroll
        for (int k = 0; k < 5; ++k)
            ob[320 + lane * 5 + k] = (acc2[k] + cvec[192 + lane] * ys[4 + k]) * inv_s8;
    }
}

extern "C" void kernel_launch(void* const* d_in, const int* in_sizes, int n_in,
                              void* d_out, int out_size, void* d_ws, size_t ws_size,
                              hipStream_t stream)
{
    const float* edge_attr    = (const float*)d_in[1];
    const float* edge_scalars = (const float*)d_in[2];
    const int*   edge_dst     = (const int*)d_in[4];
    const float* exp_w   = (const float*)d_in[6];
    const float* exp_b   = (const float*)d_in[7];
    const float* rad_w1  = (const float*)d_in[8];
    const float* rad_b1  = (const float*)d_in[9];
    const float* g1      = (const float*)d_in[10];
    const float* bt1     = (const float*)d_in[11];
    const float* rad_w2  = (const float*)d_in[12];
    const float* rad_b2  = (const float*)d_in[13];
    const float* g2      = (const float*)d_in[14];
    const float* bt2     = (const float*)d_in[15];
    const float* rad_w3  = (const float*)d_in[16];
    const float* rad_off = (const float*)d_in[17];
    const float* pw0     = (const float*)d_in[18];
    const float* pw1     = (const float*)d_in[19];
    const float* pw2     = (const float*)d_in[20];
    const float* proj_b  = (const float*)d_in[21];

    // Workspace layout (~24.2 MB):
    float* M       = (float*)d_ws;                        // 14336
    float* cvec    = M + 64 * 224;                        // 224
    float* h2csr   = cvec + 224;                          // 80000*64
    float* ya_csr  = h2csr + (size_t)NEDGES * 64;         // 80000*9
    int*   counts  = (int*)(ya_csr + (size_t)NEDGES * 9); // 10000
    int*   offsets = counts + NNODES;                     // 10001
    int*   pos_of  = offsets + NNODES + 1;                // 80000

    hipMemsetAsync(counts, 0, NNODES * sizeof(int), stream);
    precompute_and_hist<<<165, 256, 0, stream>>>(exp_w, exp_b, rad_w3, rad_off,
        pw0, pw1, pw2, M, cvec, edge_dst, counts);
    scan_counts<<<1, 1024, 0, stream>>>(counts, offsets);
    scatter_edges<<<(NEDGES + 255) / 256, 256, 0, stream>>>(edge_dst, edge_attr,
        offsets, counts, pos_of, ya_csr);
    edge_h2<<<NEDGES / 32, 256, 0, stream>>>(edge_scalars, pos_of,
        rad_w1, rad_b1, g1, bt1, rad_w2, rad_b2, g2, bt2, h2csr);
    node_gather<<<NNODES / 4, 256, 0, stream>>>(h2csr, ya_csr, offsets,
        M, cvec, proj_b, (float*)d_out);
}

// Round 4
// 153.469 us; speedup vs baseline: 2.9577x; 1.0125x over previous
//
#include <hip/hip_runtime.h>
#include <math.h>

// EdgeDegreeEmbeddingNetwork — algebraically reduced, scatter-free, CSR-ordered.
//
//   x0[u]   = exp_w[u] + exp_b[u]
//   h2      = silu(LN(silu(LN(es@W1+b1))@W2+b2))            (E,64)
//   out[n]  = contract(M, T[n]) + c ⊗ ysum[n] + cnt[n]*proj_b   (/sqrt 8)
//   T[n][u][k] = Σ_{e→n} h2[e,u]*y[e,k]
//
// Pipeline: memset -> [Mc + dst-histogram] -> scan(shuffle) ->
//           edge_h2 (LDS-broadcast MLP, inline CSR pos, writes h2csr+order) ->
//           node_gather (M staged in LDS, 16 nodes/block).
//
// edge_h2 v2: es tile (16 edges x 128) cooperatively vector-loaded into LDS,
// consumed via same-address ds_read_b128 broadcasts (in-order lgkm waits, no
// scalar-cache serialization). h1 round-trips through the same wave-private
// LDS region so GEMM2 also uses broadcasts instead of 1024 v_readlanes.

#define NEDGES 80000
#define NNODES 10000
#define EPW 16  // edges per wave

// ---- Fused: precompute M (64x224), c (224)  +  dst histogram ----------------
__global__ __launch_bounds__(256) void precompute_and_hist(
    const float* __restrict__ exp_w, const float* __restrict__ exp_b,
    const float* __restrict__ rad_w3,     // 64 x 960
    const float* __restrict__ rad_offset, // 960
    const float* __restrict__ proj_w0,    // 224 x 128 (rows 0..127 live)
    const float* __restrict__ proj_w1,    // 384 x 64
    const float* __restrict__ proj_w2,    // 352 x 32
    float* __restrict__ M, float* __restrict__ cvec,
    const int* __restrict__ edge_dst, int* __restrict__ counts)
{
    if (blockIdx.x >= 65) {
        int b = blockIdx.x - 65;
        for (int e = b * 256 + threadIdx.x; e < NEDGES; e += 100 * 256)
            atomicAdd(&counts[edge_dst[e]], 1);
        return;
    }
    __shared__ float x0[128];
    int t = threadIdx.x;
    if (t < 128) x0[t] = exp_w[t] + exp_b[t];
    __syncthreads();
    if (t >= 224) return;
    int h = blockIdx.x; // 0..63 -> M rows, 64 -> c
    const float* src = (h < 64) ? (rad_w3 + h * 960) : rad_offset;
    float acc = 0.0f;
    if (t < 128) {
#pragma unroll 4
        for (int u = 0; u < 128; ++u) acc += src[u] * x0[u] * proj_w0[u * 128 + t];
    } else if (t < 192) {
        int o = t - 128;
#pragma unroll 4
        for (int u = 0; u < 128; ++u) acc += src[128 + u] * x0[u] * proj_w1[u * 64 + o];
    } else {
        int o = t - 192;
#pragma unroll 4
        for (int u = 0; u < 128; ++u) acc += src[256 + u] * x0[u] * proj_w2[u * 32 + o];
    }
    if (h < 64) M[h * 224 + t] = acc;
    else        cvec[t] = acc;
}

// ---- CSR: exclusive scan of counts via wave shuffles (2 barriers) -----------
__global__ __launch_bounds__(1024) void scan_counts(
    int* __restrict__ counts,   // in: counts, out: zeroed (reused as cursor)
    int* __restrict__ offsets)  // NNODES+1
{
    __shared__ int wsum[16];
    const int t = threadIdx.x;
    const int lane = t & 63, w = t >> 6;
    const int base = t * 10;
    int local[10];
    int s = 0;
#pragma unroll
    for (int i = 0; i < 10; ++i) {
        int idx = base + i;
        int v = (idx < NNODES) ? counts[idx] : 0;
        local[i] = s;
        s += v;
    }
    int incl = s;
#pragma unroll
    for (int off = 1; off < 64; off <<= 1) {
        int up = __shfl_up(incl, off, 64);
        if (lane >= off) incl += up;
    }
    if (lane == 63) wsum[w] = incl;
    __syncthreads();
    if (t < 16) {
        int v = wsum[t];
#pragma unroll
        for (int off = 1; off < 16; off <<= 1) {
            int up = __shfl_up(v, off, 64);
            if (t >= off) v += up;
        }
        wsum[t] = v; // inclusive per-wave prefix
    }
    __syncthreads();
    int wbase = (w == 0) ? 0 : wsum[w - 1];
    int excl = wbase + incl - s;
#pragma unroll
    for (int i = 0; i < 10; ++i) {
        int idx = base + i;
        if (idx < NNODES) {
            offsets[idx] = excl + local[i];
            counts[idx] = 0; // becomes the scatter cursor
        }
    }
    if (t == 1023) offsets[NNODES] = excl + s;
}

// ---- Phase A: per-edge radial MLP via LDS broadcasts, inline CSR pos --------
__global__ __launch_bounds__(256) void edge_h2(
    const float* __restrict__ edge_scalars, // E x 128
    const int*   __restrict__ edge_dst,     // E
    const int*   __restrict__ offsets,      // NNODES+1
    int*         __restrict__ cursor,       // NNODES (zeroed by scan)
    const float* __restrict__ rad_w1,       // 128 x 64
    const float* __restrict__ rad_b1,
    const float* __restrict__ g1, const float* __restrict__ bt1,
    const float* __restrict__ rad_w2,       // 64 x 64
    const float* __restrict__ rad_b2,
    const float* __restrict__ g2, const float* __restrict__ bt2,
    float* __restrict__ h2csr,              // E x 64 (CSR row order)
    int*   __restrict__ order)              // E (CSR pos -> edge id)
{
    __shared__ float lds[4][EPW * 128];     // 8 KB per wave, wave-private
    const int lane = threadIdx.x & 63;
    const int wid  = threadIdx.x >> 6;
    const int e0   = (blockIdx.x * 4 + wid) * EPW;
    float* sm = lds[wid];

    // ---- stage es tile (16 edges x 128 floats) into LDS, coalesced ---------
    {
        const float* src = edge_scalars + (size_t)e0 * 128;
#pragma unroll
        for (int i = 0; i < 8; ++i) {
            int idx4 = i * 64 + lane;
            float4 v = *(const float4*)(src + idx4 * 4);
            *(float4*)(sm + idx4 * 4) = v;
        }
    }

    // ---- CSR position for this wave's edges (lanes 0..15), write order -----
    int posv = 0;
    if (lane < EPW) {
        int e = e0 + lane;
        int d = edge_dst[e];
        posv = offsets[d] + atomicAdd(&cursor[d], 1);
        order[posv] = e;
    }

    // ---- GEMM1: a[e] = b1[lane] + sum_u es[e][u]*W1[u][lane] ---------------
    float a[EPW];
    {
        float b = rad_b1[lane];
#pragma unroll
        for (int e = 0; e < EPW; ++e) a[e] = b;
    }
#pragma unroll 2
    for (int u0 = 0; u0 < 128; u0 += 8) {
        float w0 = rad_w1[(u0 + 0) * 64 + lane];
        float w1 = rad_w1[(u0 + 1) * 64 + lane];
        float w2 = rad_w1[(u0 + 2) * 64 + lane];
        float w3 = rad_w1[(u0 + 3) * 64 + lane];
        float w4 = rad_w1[(u0 + 4) * 64 + lane];
        float w5 = rad_w1[(u0 + 5) * 64 + lane];
        float w6 = rad_w1[(u0 + 6) * 64 + lane];
        float w7 = rad_w1[(u0 + 7) * 64 + lane];
#pragma unroll
        for (int e = 0; e < EPW; ++e) {
            float4 p = *(const float4*)(sm + e * 128 + u0);     // broadcast
            float4 q = *(const float4*)(sm + e * 128 + u0 + 4); // broadcast
            a[e] += w0 * p.x + w1 * p.y + w2 * p.z + w3 * p.w
                  + w4 * q.x + w5 * q.y + w6 * q.z + w7 * q.w;
        }
    }

    // ---- LN1 + silu; h1 goes back to (wave-private) LDS --------------------
    {
        float s1v[EPW], s2v[EPW];
#pragma unroll
        for (int e = 0; e < EPW; ++e) { s1v[e] = a[e]; s2v[e] = a[e] * a[e]; }
#pragma unroll
        for (int off = 32; off > 0; off >>= 1) {
#pragma unroll
            for (int e = 0; e < EPW; ++e) {
                s1v[e] += __shfl_xor(s1v[e], off, 64);
                s2v[e] += __shfl_xor(s2v[e], off, 64);
            }
        }
        float g = g1[lane], b = bt1[lane];
#pragma unroll
        for (int e = 0; e < EPW; ++e) {
            float mu  = s1v[e] * (1.0f / 64.0f);
            float var = s2v[e] * (1.0f / 64.0f) - mu * mu;
            float y   = (a[e] - mu) * rsqrtf(var + 1e-5f) * g + b;
            float h   = y / (1.0f + __expf(-y));
            sm[e * 64 + lane] = h; // overwrite es region (reads all done)
        }
    }

    // ---- GEMM2: c[e] = b2[lane] + sum_u h1[e][u]*W2[u][lane] ---------------
    float c[EPW];
    {
        float b = rad_b2[lane];
#pragma unroll
        for (int e = 0; e < EPW; ++e) c[e] = b;
    }
#pragma unroll 2
    for (int u0 = 0; u0 < 64; u0 += 8) {
        float w0 = rad_w2[(u0 + 0) * 64 + lane];
        float w1 = rad_w2[(u0 + 1) * 64 + lane];
        float w2 = rad_w2[(u0 + 2) * 64 + lane];
        float w3 = rad_w2[(u0 + 3) * 64 + lane];
        float w4 = rad_w2[(u0 + 4) * 64 + lane];
        float w5 = rad_w2[(u0 + 5) * 64 + lane];
        float w6 = rad_w2[(u0 + 6) * 64 + lane];
        float w7 = rad_w2[(u0 + 7) * 64 + lane];
#pragma unroll
        for (int e = 0; e < EPW; ++e) {
            float4 p = *(const float4*)(sm + e * 64 + u0);     // broadcast
            float4 q = *(const float4*)(sm + e * 64 + u0 + 4); // broadcast
            c[e] += w0 * p.x + w1 * p.y + w2 * p.z + w3 * p.w
                  + w4 * q.x + w5 * q.y + w6 * q.z + w7 * q.w;
        }
    }

    // ---- LN2 + silu, store rows at CSR positions ---------------------------
    {
        float s1v[EPW], s2v[EPW];
#pragma unroll
        for (int e = 0; e < EPW; ++e) { s1v[e] = c[e]; s2v[e] = c[e] * c[e]; }
#pragma unroll
        for (int off = 32; off > 0; off >>= 1) {
#pragma unroll
            for (int e = 0; e < EPW; ++e) {
                s1v[e] += __shfl_xor(s1v[e], off, 64);
                s2v[e] += __shfl_xor(s2v[e], off, 64);
            }
        }
        float g = g2[lane], b = bt2[lane];
#pragma unroll
        for (int e = 0; e < EPW; ++e) {
            float mu  = s1v[e] * (1.0f / 64.0f);
            float var = s2v[e] * (1.0f / 64.0f) - mu * mu;
            float y   = (c[e] - mu) * rsqrtf(var + 1e-5f) * g + b;
            float h   = y / (1.0f + __expf(-y));
            int p = __builtin_amdgcn_readlane(posv, e); // uniform SGPR
            h2csr[(size_t)p * 64 + lane] = h;           // coalesced 256B
        }
    }
}

// ---- Phase B: 16 nodes/block, M staged in LDS, streaming reads, plain writes
__global__ __launch_bounds__(1024) void node_gather(
    const float* __restrict__ h2csr,     // E x 64 (CSR order)
    const float* __restrict__ edge_attr, // E x 9 (original order)
    const int*   __restrict__ order,     // E (CSR pos -> edge id)
    const int*   __restrict__ offsets,   // NNODES+1
    const float* __restrict__ M,         // 64 x 224
    const float* __restrict__ cvec,      // 224
    const float* __restrict__ proj_b,    // 128
    float* __restrict__ out)             // NNODES x 480
{
    __shared__ float ldsM[64 * 224];     // 56 KB, shared by 16 waves
    for (int i = threadIdx.x; i < 64 * 224; i += 1024) ldsM[i] = M[i];
    __syncthreads();

    const int lane = threadIdx.x & 63;
    const int n = __builtin_amdgcn_readfirstlane(blockIdx.x * 16 + (threadIdx.x >> 6));
    const int s0 = offsets[n], s1 = offsets[n + 1];

    float T[9]  = {0, 0, 0, 0, 0, 0, 0, 0, 0};
    float ys[9] = {0, 0, 0, 0, 0, 0, 0, 0, 0};
    for (int i = s0; i < s1; ++i) {
        float hv = h2csr[(size_t)i * 64 + lane];   // coalesced stream
        int e = order[i];                          // uniform s_load
        const float* ya = edge_attr + (size_t)e * 9;
#pragma unroll
        for (int k = 0; k < 9; ++k) {
            float y = ya[k];
            T[k] += hv * y;
            ys[k] += y;
        }
    }

    const int l32 = lane & 31;
    float acc0a = 0.0f, acc0b = 0.0f;
    float acc1[3] = {0, 0, 0};
    float acc2[5] = {0, 0, 0, 0, 0};
#pragma unroll 4
    for (int u = 0; u < 64; ++u) {
        const float* Mu = ldsM + u * 224;
        float m0a = Mu[lane];        // lane-indexed, conflict-free
        float m0b = Mu[64 + lane];
        float m1  = Mu[128 + lane];
        float m2  = Mu[192 + l32];
        float t0 = __builtin_bit_cast(float, __builtin_amdgcn_readlane(
                       __builtin_bit_cast(int, T[0]), u));
        acc0a += m0a * t0;
        acc0b += m0b * t0;
#pragma unroll
        for (int k = 0; k < 3; ++k)
            acc1[k] += m1 * __builtin_bit_cast(float, __builtin_amdgcn_readlane(
                                __builtin_bit_cast(int, T[1 + k]), u));
#pragma unroll
        for (int k = 0; k < 5; ++k)
            acc2[k] += m2 * __builtin_bit_cast(float, __builtin_amdgcn_readlane(
                                __builtin_bit_cast(int, T[4 + k]), u));
    }

    constexpr float inv_s8 = 0.35355339059327373f; // 1/sqrt(8)
    const float cnt = (float)(s1 - s0);
    float* ob = out + (size_t)n * 480;
    ob[lane]      = (acc0a + cvec[lane] * ys[0]      + cnt * proj_b[lane])      * inv_s8;
    ob[64 + lane] = (acc0b + cvec[64 + lane] * ys[0] + cnt * proj_b[64 + lane]) * inv_s8;
#pragma unroll
    for (int k = 0; k < 3; ++k)
        ob[128 + lane * 3 + k] = (acc1[k] + cvec[128 + lane] * ys[1 + k]) * inv_s8;
    if (lane < 32) {
#pragma unroll
        for (int k = 0; k < 5; ++k)
            ob[320 + lane * 5 + k] = (acc2[k] + cvec[192 + lane] * ys[4 + k]) * inv_s8;
    }
}

extern "C" void kernel_launch(void* const* d_in, const int* in_sizes, int n_in,
                              void* d_out, int out_size, void* d_ws, size_t ws_size,
                              hipStream_t stream)
{
    const float* edge_attr    = (const float*)d_in[1];
    const float* edge_scalars = (const float*)d_in[2];
    const int*   edge_dst     = (const int*)d_in[4];
    const float* exp_w   = (const float*)d_in[6];
    const float* exp_b   = (const float*)d_in[7];
    const float* rad_w1  = (const float*)d_in[8];
    const float* rad_b1  = (const float*)d_in[9];
    const float* g1      = (const float*)d_in[10];
    const float* bt1     = (const float*)d_in[11];
    const float* rad_w2  = (const float*)d_in[12];
    const float* rad_b2  = (const float*)d_in[13];
    const float* g2      = (const float*)d_in[14];
    const float* bt2     = (const float*)d_in[15];
    const float* rad_w3  = (const float*)d_in[16];
    const float* rad_off = (const float*)d_in[17];
    const float* pw0     = (const float*)d_in[18];
    const float* pw1     = (const float*)d_in[19];
    const float* pw2     = (const float*)d_in[20];
    const float* proj_b  = (const float*)d_in[21];

    // Workspace layout (~21 MB):
    float* M       = (float*)d_ws;                         // 14336
    float* cvec    = M + 64 * 224;                         // 224
    float* h2csr   = cvec + 224;                           // 80000*64
    int*   counts  = (int*)(h2csr + (size_t)NEDGES * 64);  // 10000
    int*   offsets = counts + NNODES;                      // 10001
    int*   order   = offsets + NNODES + 1;                 // 80000

    hipMemsetAsync(counts, 0, NNODES * sizeof(int), stream);
    precompute_and_hist<<<165, 256, 0, stream>>>(exp_w, exp_b, rad_w3, rad_off,
        pw0, pw1, pw2, M, cvec, edge_dst, counts);
    scan_counts<<<1, 1024, 0, stream>>>(counts, offsets);
    edge_h2<<<NEDGES / (4 * EPW), 256, 0, stream>>>(edge_scalars, edge_dst,
        offsets, counts, rad_w1, rad_b1, g1, bt1, rad_w2, rad_b2, g2, bt2,
        h2csr, order);
    node_gather<<<NNODES / 16, 1024, 0, stream>>>(h2csr, edge_attr, order,
        offsets, M, cvec, proj_b, (float*)d_out);
}